// Round 6
// baseline (2732.900 us; speedup 1.0000x reference)
//
#include <hip/hip_runtime.h>
#include <hip/hip_fp16.h>

#define NB 64
#define NT 512
#define ND 128
#define NH 256
#define G4 1024                     // 4*H
#define NBT (NB*NT)                 // 32768
#define CSTRIDE ((size_t)NBT * G4)  // elements per interval component of px
#define OSTRIDE ((size_t)NBT * NH)  // elements per interval component of out

typedef _Float16 f16x2 __attribute__((ext_vector_type(2)));

__device__ __forceinline__ float fdot2u(unsigned a, unsigned b, float c) {
  return __builtin_amdgcn_fdot2(__builtin_bit_cast(f16x2, a),
                                __builtin_bit_cast(f16x2, b), c, false);
}

// val-only: 4 fdot2
__device__ __forceinline__ void accV(uint4 w, uint4 hv, float& av) {
  av = fdot2u(w.x, hv.x, av);
  av = fdot2u(w.y, hv.y, av);
  av = fdot2u(w.z, hv.z, av);
  av = fdot2u(w.w, hv.w, av);
}
// interval: mid += w.hm, rad += |w|.hr
__device__ __forceinline__ void accMR(uint4 w, uint4 hm, uint4 hr, float& am, float& ar) {
  const unsigned M = 0x7FFF7FFFu;
  am = fdot2u(w.x, hm.x, am); ar = fdot2u(w.x & M, hr.x, ar);
  am = fdot2u(w.y, hm.y, am); ar = fdot2u(w.y & M, hr.y, ar);
  am = fdot2u(w.z, hm.z, am); ar = fdot2u(w.z & M, hr.z, ar);
  am = fdot2u(w.w, hm.w, am); ar = fdot2u(w.w & M, hr.w, ar);
}

// quad all-reduce via DPP quad_perm (verified R2-R4)
__device__ __forceinline__ float qsum4(float x) {
  int v = __builtin_amdgcn_update_dpp(0, __builtin_bit_cast(int, x), 0xB1, 0xF, 0xF, true);
  x += __builtin_bit_cast(float, v);
  v = __builtin_amdgcn_update_dpp(0, __builtin_bit_cast(int, x), 0x4E, 0xF, 0xF, true);
  x += __builtin_bit_cast(float, v);
  return x;
}
__device__ __forceinline__ float sel4(float x0, float x1, float x2, float x3, int q) {
  float a = (q & 1) ? x1 : x0;
  float b = (q & 1) ? x3 : x2;
  return (q & 2) ? b : a;
}

__device__ __forceinline__ float rcpf(float x) { return __builtin_amdgcn_rcpf(x); }
__device__ __forceinline__ float gact(float x, bool is_tanh) {
  float s = is_tanh ? -2.0f : -1.0f;
  float e = __expf(s * x);
  float r = rcpf(1.0f + e);
  return is_tanh ? fmaf(2.0f, r, -1.0f) : r;
}
__device__ __forceinline__ float tanh_f(float x) {
  return fmaf(2.0f, rcpf(1.0f + __expf(-2.0f * x)), -1.0f);
}
// chain-shaped 4-way min/max -> v_min3/v_max3 fusion (2 ops instead of 3)
__device__ __forceinline__ float min4c(float a, float b, float c, float d) {
  return fminf(fminf(fminf(a, b), c), d);
}
__device__ __forceinline__ float max4c(float a, float b, float c, float d) {
  return fmaxf(fmaxf(fmaxf(a, b), c), d);
}

// Pack weights f32->f16.  (R4 layout, verified)
// P4[(r*8+c8)*1024 + t] = Whh[j=(t>>2)*4 + r][k=(t&3)*64 + c8*8 ..+8], r=0..3
//   (R10 tiering: r=0,1,2 VGPR-pinned; r=3 streamed from global/L2)
// PIH[(c*8+r)*512 + t]  = Wih[(t>>2)*8 + r][(t&3)*32 + c*8 ..+8]  (px kernel, verified R2-R4)
__global__ void conv_w_kernel(const float* __restrict__ Whh, const float* __restrict__ Wih,
                              uint4* __restrict__ P4, uint4* __restrict__ PIH) {
  int o = blockIdx.x * 256 + threadIdx.x;
  union { uint4 u; __half h[8]; } p;
  if (o < 32768) {
    int t = o & 1023, rc = o >> 10, r = rc >> 3, c8 = rc & 7;
    int j = ((t >> 2) << 2) + r, k = ((t & 3) << 6) + c8 * 8;
    const float* s = Whh + j * NH + k;
#pragma unroll
    for (int i = 0; i < 8; ++i) p.h[i] = __float2half(s[i]);
    P4[o] = p.u;
  } else if (o < 49152) {
    int o3 = o - 32768;
    int t = o3 & 511, rc = o3 >> 9, c = rc >> 3, r = rc & 7;
    int j = ((t >> 2) << 3) + r, k = ((t & 3) << 5) + c * 8;
    const float* s = Wih + j * ND + k;
#pragma unroll
    for (int i = 0; i < 8; ++i) p.h[i] = __float2half(s[i]);
    PIH[o3] = p.u;
  }
}

// px kernel: R2-R4 verified structure. R9: bias folded in (b0/b1 per emitted
// row), intv components stored INTERLEAVED as half2(lb,ub) per row at CSTRIDE.
// Lane t emits G4-rows 2t and 2t+1 (j0=2t, j1=2t+1; verified mapping).
__global__ __launch_bounds__(512, 2)
void px_kernel(const float* __restrict__ xv, const float* __restrict__ xl,
               const float* __restrict__ xu, const uint4* __restrict__ PIH,
               const float* __restrict__ bias, __half* __restrict__ px) {
  __shared__ __align__(16) __half sv[32 * ND];
  __shared__ __align__(16) __half sm[32 * ND];
  __shared__ __align__(16) __half sr[32 * ND];
  const int t = threadIdx.x;
  const int q = t & 3;
  const int r0 = blockIdx.x * 32;
  const float b0 = bias[2 * t];
  const float b1 = bias[2 * t + 1];
  uint4 w[4][8];
#pragma unroll
  for (int c = 0; c < 4; ++c)
#pragma unroll
    for (int r = 0; r < 8; ++r)
      w[c][r] = PIH[((c * 8 + r) << 9) + t];
  {
    const float4* v4 = (const float4*)(xv + (size_t)r0 * ND);
    const float4* l4 = (const float4*)(xl + (size_t)r0 * ND);
    const float4* u4 = (const float4*)(xu + (size_t)r0 * ND);
    __half2* sv2 = (__half2*)sv; __half2* sm2 = (__half2*)sm; __half2* sr2 = (__half2*)sr;
    for (int i = t; i < 1024; i += 512) {
      float4 v = v4[i], l = l4[i], u = u4[i];
      sv2[2*i]   = __floats2half2_rn(v.x, v.y);
      sv2[2*i+1] = __floats2half2_rn(v.z, v.w);
      sm2[2*i]   = __floats2half2_rn(0.5f*(l.x+u.x), 0.5f*(l.y+u.y));
      sm2[2*i+1] = __floats2half2_rn(0.5f*(l.z+u.z), 0.5f*(l.w+u.w));
      sr2[2*i]   = __floats2half2_rn(0.5f*(u.x-l.x), 0.5f*(u.y-l.y));
      sr2[2*i+1] = __floats2half2_rn(0.5f*(u.z-l.z), 0.5f*(u.w-l.w));
    }
  }
  __syncthreads();
  const uint4* bv = (const uint4*)sv;
  const uint4* bm = (const uint4*)sm;
  const uint4* br = (const uint4*)sr;
  __half2* pxV = (__half2*)px;                    // val comp, half2 per 2 rows
  __half2* pxI = (__half2*)(px + CSTRIDE);        // intv comp, half2(lb,ub) per row
  for (int rr = 0; rr < 32; ++rr) {
    uint4 hv[4], hm[4], hr[4];
    const int base = rr * 16 + q * 4;
#pragma unroll
    for (int i = 0; i < 4; ++i) { hv[i] = bv[base+i]; hm[i] = bm[base+i]; hr[i] = br[base+i]; }
    float A[8][3];
#pragma unroll
    for (int r = 0; r < 8; ++r) { A[r][0] = 0.f; A[r][1] = 0.f; A[r][2] = 0.f; }
#pragma unroll
    for (int c = 0; c < 4; ++c)
#pragma unroll
      for (int r = 0; r < 8; ++r) {
        accV(w[c][r], hv[c], A[r][0]);
        accMR(w[c][r], hm[c], hr[c], A[r][1], A[r][2]);
      }
#pragma unroll
    for (int r = 0; r < 8; ++r) {
      A[r][0] = qsum4(A[r][0]); A[r][1] = qsum4(A[r][1]); A[r][2] = qsum4(A[r][2]);
    }
    float v0 = sel4(A[0][0], A[2][0], A[4][0], A[6][0], q) + b0;
    float m0 = sel4(A[0][1], A[2][1], A[4][1], A[6][1], q) + b0;
    float d0 = sel4(A[0][2], A[2][2], A[4][2], A[6][2], q);
    float v1 = sel4(A[1][0], A[3][0], A[5][0], A[7][0], q) + b1;
    float m1 = sel4(A[1][1], A[3][1], A[5][1], A[7][1], q) + b1;
    float d1 = sel4(A[1][2], A[3][2], A[5][2], A[7][2], q);
    size_t ob = (size_t)(r0 + rr) * G4;
    pxV[(ob >> 1) + t] = __floats2half2_rn(v0, v1);
    union { uint2 u; __half2 h[2]; } pi;
    pi.h[0] = __floats2half2_rn(m0 - d0, m0 + d0);  // row 2t: (lb, ub)
    pi.h[1] = __floats2half2_rn(m1 - d1, m1 + d1);  // row 2t+1
    *(uint2*)(pxI + ob + 2 * t) = pi.u;
  }
}

// Recurrence (R9 structure, verified; R10 = tier-3 LDS -> streamed global):
// 128 blocks: blockIdx<64 -> val LSTM for batch row b; >=64 -> interval LSTM.
// 1024 threads: q=t&3 K-quarter, 4 rows/thread (j = (t>>2)*4+r); after quad
// reduce+sel4 thread t owns gate row t exactly.
// W tiers: r=0,1,2 VGPR-pinned (96 regs, asm); r=3 streamed from global each
// step (128 KiB/block, L2-resident, coalesced dwordx4 — uses the idle vmem
// pipe instead of the saturated LDS pipe). Stream pointer laundered per step
// so the compiler cannot hoist the loop-invariant loads into registers.
// px prefetched one step ahead (bias pre-folded; intv = one half2(lb,ub)
// load); out stores deferred one step. sG intv = float2(gl,gu).
__global__ __launch_bounds__(1024, 4)
void lstm_kernel(const uint4* __restrict__ P4, const __half* __restrict__ px,
                 float* __restrict__ out) {
  __shared__ __align__(16) __half sH[2][4][72];   // [slot][q][64+8 pad]; val: slot0=hv; intv: 0=hm,1=hr
  __shared__ __align__(16) float sG[2][G4];       // val: sG[0][row]; intv: aliased as float2[row]=(gl,gu)
  float2* sGp = (float2*)sG;
  const int t = threadIdx.x;
  const bool intv = blockIdx.x >= NB;
  const int b = intv ? blockIdx.x - NB : blockIdx.x;
  const int q = t & 3;
  // pinned W rows r=0,1,2 (96 VGPRs)
  uint4 Wp[3][8];
#pragma unroll
  for (int r = 0; r < 3; ++r)
#pragma unroll
    for (int c8 = 0; c8 < 8; ++c8)
      Wp[r][c8] = P4[((r * 8 + c8) << 10) + t];
#pragma unroll
  for (int r = 0; r < 3; ++r)
#pragma unroll
    for (int c8 = 0; c8 < 8; ++c8)
      asm volatile("" : "+v"(Wp[r][c8].x), "+v"(Wp[r][c8].y),
                        "+v"(Wp[r][c8].z), "+v"(Wp[r][c8].w));
  const bool is_tanh = ((t >> 8) == 2);           // rows 512..767 = gate g
  if (t < 288) ((unsigned*)sH)[t] = 0u;           // zero h (1152 B)
  __syncthreads();
  float* outb = out + (size_t)b * NT * NH;
  const uint4* P4s = P4 + (24 << 10) + t;         // streamed tier r=3

  if (!intv) {
    // ---------------- point-value LSTM ----------------
    const __half* pxb = px + (size_t)b * NT * G4;
    float cv = 0.f, hv_p = 0.f;
    float pv = __half2float(pxb[t]);
    for (int ts = 0; ts < NT; ++ts) {
      if (ts > 0 && t < NH) outb[(size_t)(ts - 1) * NH + t] = hv_p;
      const int tsn = (ts + 1 < NT) ? ts + 1 : ts;
      float nv = __half2float(pxb[(size_t)tsn * G4 + t]);
      const uint4* p3 = P4s;
      asm volatile("" : "+v"(p3));                // defeat load hoisting
      float A0 = 0.f, A1 = 0.f, A2 = 0.f, A3 = 0.f;
#pragma unroll
      for (int c8 = 0; c8 < 8; ++c8) {
        uint4 ws3 = p3[c8 << 10];                       // streamed r=3 (L2)
        uint4 hv = *(const uint4*)(&sH[0][q][c8 * 8]);  // quad-distinct broadcast
        accV(Wp[0][c8], hv, A0);
        accV(Wp[1][c8], hv, A1);
        accV(Wp[2][c8], hv, A2);
        accV(ws3, hv, A3);
      }
      A0 = qsum4(A0); A1 = qsum4(A1); A2 = qsum4(A2); A3 = qsum4(A3);
      float av = sel4(A0, A1, A2, A3, q);               // row t
      float gt = gact(pv + av, is_tanh);                // bias pre-folded in px
      sG[0][t] = gt;
      __syncthreads();
      if (t < NH) {
        float iv = sG[0][t], fv = sG[0][NH + t], gv = sG[0][2 * NH + t], ov = sG[0][3 * NH + t];
        cv = fmaf(fv, cv, iv * gv);
        float hvn = ov * tanh_f(cv);
        hv_p = hvn;
        sH[0][t >> 6][t & 63] = __float2half(hvn);
      }
      __syncthreads();
      pv = nv;
    }
    if (t < NH) outb[(size_t)(NT - 1) * NH + t] = hv_p;
  } else {
    // ---------------- interval (lb/ub) LSTM ----------------
    const __half2* pI = (const __half2*)(px + CSTRIDE) + (size_t)b * NT * G4;
    float cl = 0.f, cu = 0.f, hl_p = 0.f, hu_p = 0.f;
    __half2 plu = pI[t];
    for (int ts = 0; ts < NT; ++ts) {
      if (ts > 0 && t < NH) {
        size_t o = (size_t)(ts - 1) * NH + t;
        outb[OSTRIDE + o] = hl_p; outb[2 * OSTRIDE + o] = hu_p;
      }
      const int tsn = (ts + 1 < NT) ? ts + 1 : ts;
      __half2 nlu = pI[(size_t)tsn * G4 + t];
      const uint4* p3 = P4s;
      asm volatile("" : "+v"(p3));                // defeat load hoisting
      float M0 = 0.f, M1 = 0.f, M2 = 0.f, M3 = 0.f;
      float R0 = 0.f, R1 = 0.f, R2 = 0.f, R3 = 0.f;
#pragma unroll
      for (int c8 = 0; c8 < 8; ++c8) {
        uint4 ws3 = p3[c8 << 10];                       // streamed r=3 (L2)
        uint4 hm = *(const uint4*)(&sH[0][q][c8 * 8]);
        uint4 hr = *(const uint4*)(&sH[1][q][c8 * 8]);
        accMR(Wp[0][c8], hm, hr, M0, R0);
        accMR(Wp[1][c8], hm, hr, M1, R1);
        accMR(Wp[2][c8], hm, hr, M2, R2);
        accMR(ws3, hm, hr, M3, R3);
      }
      M0 = qsum4(M0); M1 = qsum4(M1); M2 = qsum4(M2); M3 = qsum4(M3);
      R0 = qsum4(R0); R1 = qsum4(R1); R2 = qsum4(R2); R3 = qsum4(R3);
      float m = sel4(M0, M1, M2, M3, q);                // row t
      float d = sel4(R0, R1, R2, R3, q);
      float pl = __low2float(plu), pu = __high2float(plu);  // bias pre-folded
      float gl = gact(pl + (m - d), is_tanh);
      float gu = gact(pu + (m + d), is_tanh);
      sGp[t] = make_float2(gl, gu);                     // one b64 write
      __syncthreads();
      if (t < NH) {
        float2 gi = sGp[t], gf = sGp[NH + t], gg = sGp[2 * NH + t], go = sGp[3 * NH + t];
        float il = gi.x, iu = gi.y, fl = gf.x, fu = gf.y;
        float gl_ = gg.x, gu_ = gg.y, ol = go.x, ou = go.y;
        float p0 = fl*cl, p1 = fl*cu, p2 = fu*cl, p3 = fu*cu;
        float fcl = min4c(p0, p1, p2, p3);
        float fcu = max4c(p0, p1, p2, p3);
        p0 = il*gl_; p1 = il*gu_; p2 = iu*gl_; p3 = iu*gu_;
        float igl = min4c(p0, p1, p2, p3);
        float igu = max4c(p0, p1, p2, p3);
        cl = fcl + igl; cu = fcu + igu;
        float tl = tanh_f(cl), tu = tanh_f(cu);
        p0 = ol*tl; p1 = ol*tu; p2 = ou*tl; p3 = ou*tu;
        float hl = min4c(p0, p1, p2, p3);
        float hu = max4c(p0, p1, p2, p3);
        hl_p = hl; hu_p = hu;
        sH[0][t >> 6][t & 63] = __float2half(0.5f * (hl + hu));
        sH[1][t >> 6][t & 63] = __float2half(0.5f * (hu - hl));
      }
      __syncthreads();
      plu = nlu;
    }
    if (t < NH) {
      size_t o = (size_t)(NT - 1) * NH + t;
      outb[OSTRIDE + o] = hl_p; outb[2 * OSTRIDE + o] = hu_p;
    }
  }
}

extern "C" void kernel_launch(void* const* d_in, const int* in_sizes, int n_in,
                              void* d_out, int out_size, void* d_ws, size_t ws_size,
                              hipStream_t stream) {
  const float* xv   = (const float*)d_in[0];
  const float* xl   = (const float*)d_in[1];
  const float* xu   = (const float*)d_in[2];
  const float* Wih  = (const float*)d_in[3];
  const float* Whh  = (const float*)d_in[4];
  const float* bias = (const float*)d_in[5];
  float* out = (float*)d_out;
  char* ws = (char*)d_ws;
  uint4*  P4  = (uint4*)ws;                    // 512 KiB (recurrent W, 4-row layout)
  uint4*  PIH = (uint4*)(ws + 512 * 1024);     // 256 KiB (px weights)
  __half* px  = (__half*)(ws + 768 * 1024);    // 192 MiB (val G4 + intv 2*G4 interleaved)

  conv_w_kernel<<<192, 256, 0, stream>>>(Whh, Wih, P4, PIH);
  px_kernel<<<NBT / 32, 512, 0, stream>>>(xv, xl, xu, PIH, bias, px);
  lstm_kernel<<<2 * NB, 1024, 0, stream>>>(P4, px, out);
}

// Round 7
// 2693.142 us; speedup vs baseline: 1.0148x; 1.0148x over previous
//
#include <hip/hip_runtime.h>
#include <hip/hip_fp16.h>

#define NB 64
#define NT 512
#define ND 128
#define NH 256
#define G4 1024                     // 4*H
#define NBT (NB*NT)                 // 32768
#define CSTRIDE ((size_t)NBT * G4)  // elements per interval component of px
#define OSTRIDE ((size_t)NBT * NH)  // elements per interval component of out

typedef _Float16 f16x2 __attribute__((ext_vector_type(2)));

__device__ __forceinline__ float fdot2u(unsigned a, unsigned b, float c) {
  return __builtin_amdgcn_fdot2(__builtin_bit_cast(f16x2, a),
                                __builtin_bit_cast(f16x2, b), c, false);
}

// val-only: 4 fdot2
__device__ __forceinline__ void accV(uint4 w, uint4 hv, float& av) {
  av = fdot2u(w.x, hv.x, av);
  av = fdot2u(w.y, hv.y, av);
  av = fdot2u(w.z, hv.z, av);
  av = fdot2u(w.w, hv.w, av);
}
// interval: mid += w.hm, rad += |w|.hr
__device__ __forceinline__ void accMR(uint4 w, uint4 hm, uint4 hr, float& am, float& ar) {
  const unsigned M = 0x7FFF7FFFu;
  am = fdot2u(w.x, hm.x, am); ar = fdot2u(w.x & M, hr.x, ar);
  am = fdot2u(w.y, hm.y, am); ar = fdot2u(w.y & M, hr.y, ar);
  am = fdot2u(w.z, hm.z, am); ar = fdot2u(w.z & M, hr.z, ar);
  am = fdot2u(w.w, hm.w, am); ar = fdot2u(w.w & M, hr.w, ar);
}

// quad all-reduce via DPP quad_perm (verified R2-R4): butterfly -> all 4 lanes
// of the quad hold the full sum afterwards.
__device__ __forceinline__ float qsum4(float x) {
  int v = __builtin_amdgcn_update_dpp(0, __builtin_bit_cast(int, x), 0xB1, 0xF, 0xF, true);
  x += __builtin_bit_cast(float, v);
  v = __builtin_amdgcn_update_dpp(0, __builtin_bit_cast(int, x), 0x4E, 0xF, 0xF, true);
  x += __builtin_bit_cast(float, v);
  return x;
}
__device__ __forceinline__ float sel4(float x0, float x1, float x2, float x3, int q) {
  float a = (q & 1) ? x1 : x0;
  float b = (q & 1) ? x3 : x2;
  return (q & 2) ? b : a;
}
// quad broadcast of lane (PAT replicates source lane: 0x00/0x55/0xAA/0xFF)
// (verified R7 run)
template <int PAT>
__device__ __forceinline__ float qb(float x) {
  return __builtin_bit_cast(float,
      __builtin_amdgcn_update_dpp(0, __builtin_bit_cast(int, x), PAT, 0xF, 0xF, true));
}

__device__ __forceinline__ float rcpf(float x) { return __builtin_amdgcn_rcpf(x); }
__device__ __forceinline__ float gact(float x, bool is_tanh) {
  float s = is_tanh ? -2.0f : -1.0f;
  float e = __expf(s * x);
  float r = rcpf(1.0f + e);
  return is_tanh ? fmaf(2.0f, r, -1.0f) : r;
}
__device__ __forceinline__ float tanh_f(float x) {
  return fmaf(2.0f, rcpf(1.0f + __expf(-2.0f * x)), -1.0f);
}
// chain-shaped 4-way min/max -> v_min3/v_max3 fusion
__device__ __forceinline__ float min4c(float a, float b, float c, float d) {
  return fminf(fminf(fminf(a, b), c), d);
}
__device__ __forceinline__ float max4c(float a, float b, float c, float d) {
  return fmaxf(fmaxf(fmaxf(a, b), c), d);
}

// Pack weights f32->f16.
// P4 (R11 gate-minor quad layout, = R5's verified packing):
//   P4[((g*8+c8)<<10) + t] = Whh[(g<<8) + (t>>2)][(t&3)*64 + c8*8 ..+8]
//   g = gate (0..3): g=0,1,2 VGPR-pinned; g=3 LDS.
// PIH (R11 gate-minor row set; K-quarter/dot structure unchanged from R2-R4):
//   PIH[(c*8+r)*512 + t] = Wih[jp][(t&3)*32 + c*8 ..+8],
//   jp = ((r&3)<<8) + ((t>>2)<<1) + (r>>2)
//   -> px_kernel's unchanged sel4 then emits row ((t&1)<<9)+(t>>1) at pos 2t
//      and that row +256 at pos 2t+1, i.e. gate-minor px[ts][unit][gate].
__global__ void conv_w_kernel(const float* __restrict__ Whh, const float* __restrict__ Wih,
                              uint4* __restrict__ P4, uint4* __restrict__ PIH) {
  int o = blockIdx.x * 256 + threadIdx.x;
  union { uint4 u; __half h[8]; } p;
  if (o < 32768) {
    int t = o & 1023, rc = o >> 10, g = rc >> 3, c8 = rc & 7;
    int j = (g << 8) + (t >> 2), k = ((t & 3) << 6) + c8 * 8;
    const float* s = Whh + j * NH + k;
#pragma unroll
    for (int i = 0; i < 8; ++i) p.h[i] = __float2half(s[i]);
    P4[o] = p.u;
  } else if (o < 49152) {
    int o3 = o - 32768;
    int t = o3 & 511, rc = o3 >> 9, c = rc >> 3, r = rc & 7;
    int j = ((r & 3) << 8) + ((t >> 2) << 1) + (r >> 2);
    int k = ((t & 3) << 5) + c * 8;
    const float* s = Wih + j * ND + k;
#pragma unroll
    for (int i = 0; i < 8; ++i) p.h[i] = __float2half(s[i]);
    PIH[o3] = p.u;
  }
}

// px kernel: R2-R4 verified dot/reduce/store structure; R9 bias-fold +
// interleaved intv half2(lb,ub). R11: only PIH packing (above) and the bias
// row indices change -> emitted layout is gate-minor. Store code identical.
__global__ __launch_bounds__(512, 2)
void px_kernel(const float* __restrict__ xv, const float* __restrict__ xl,
               const float* __restrict__ xu, const uint4* __restrict__ PIH,
               const float* __restrict__ bias, __half* __restrict__ px) {
  __shared__ __align__(16) __half sv[32 * ND];
  __shared__ __align__(16) __half sm[32 * ND];
  __shared__ __align__(16) __half sr[32 * ND];
  const int t = threadIdx.x;
  const int q = t & 3;
  const int r0 = blockIdx.x * 32;
  const int jb = ((t & 1) << 9) + (t >> 1);   // row emitted at pos 2t
  const float b0 = bias[jb];
  const float b1 = bias[jb + 256];            // row emitted at pos 2t+1
  uint4 w[4][8];
#pragma unroll
  for (int c = 0; c < 4; ++c)
#pragma unroll
    for (int r = 0; r < 8; ++r)
      w[c][r] = PIH[((c * 8 + r) << 9) + t];
  {
    const float4* v4 = (const float4*)(xv + (size_t)r0 * ND);
    const float4* l4 = (const float4*)(xl + (size_t)r0 * ND);
    const float4* u4 = (const float4*)(xu + (size_t)r0 * ND);
    __half2* sv2 = (__half2*)sv; __half2* sm2 = (__half2*)sm; __half2* sr2 = (__half2*)sr;
    for (int i = t; i < 1024; i += 512) {
      float4 v = v4[i], l = l4[i], u = u4[i];
      sv2[2*i]   = __floats2half2_rn(v.x, v.y);
      sv2[2*i+1] = __floats2half2_rn(v.z, v.w);
      sm2[2*i]   = __floats2half2_rn(0.5f*(l.x+u.x), 0.5f*(l.y+u.y));
      sm2[2*i+1] = __floats2half2_rn(0.5f*(l.z+u.z), 0.5f*(l.w+u.w));
      sr2[2*i]   = __floats2half2_rn(0.5f*(u.x-l.x), 0.5f*(u.y-l.y));
      sr2[2*i+1] = __floats2half2_rn(0.5f*(u.z-l.z), 0.5f*(u.w-l.w));
    }
  }
  __syncthreads();
  const uint4* bv = (const uint4*)sv;
  const uint4* bm = (const uint4*)sm;
  const uint4* br = (const uint4*)sr;
  __half2* pxV = (__half2*)px;                    // val comp
  __half2* pxI = (__half2*)(px + CSTRIDE);        // intv comp, half2(lb,ub) per row
  for (int rr = 0; rr < 32; ++rr) {
    uint4 hv[4], hm[4], hr[4];
    const int base = rr * 16 + q * 4;
#pragma unroll
    for (int i = 0; i < 4; ++i) { hv[i] = bv[base+i]; hm[i] = bm[base+i]; hr[i] = br[base+i]; }
    float A[8][3];
#pragma unroll
    for (int r = 0; r < 8; ++r) { A[r][0] = 0.f; A[r][1] = 0.f; A[r][2] = 0.f; }
#pragma unroll
    for (int c = 0; c < 4; ++c)
#pragma unroll
      for (int r = 0; r < 8; ++r) {
        accV(w[c][r], hv[c], A[r][0]);
        accMR(w[c][r], hm[c], hr[c], A[r][1], A[r][2]);
      }
#pragma unroll
    for (int r = 0; r < 8; ++r) {
      A[r][0] = qsum4(A[r][0]); A[r][1] = qsum4(A[r][1]); A[r][2] = qsum4(A[r][2]);
    }
    float v0 = sel4(A[0][0], A[2][0], A[4][0], A[6][0], q) + b0;
    float m0 = sel4(A[0][1], A[2][1], A[4][1], A[6][1], q) + b0;
    float d0 = sel4(A[0][2], A[2][2], A[4][2], A[6][2], q);
    float v1 = sel4(A[1][0], A[3][0], A[5][0], A[7][0], q) + b1;
    float m1 = sel4(A[1][1], A[3][1], A[5][1], A[7][1], q) + b1;
    float d1 = sel4(A[1][2], A[3][2], A[5][2], A[7][2], q);
    size_t ob = (size_t)(r0 + rr) * G4;
    pxV[(ob >> 1) + t] = __floats2half2_rn(v0, v1);
    union { uint2 u; __half2 h[2]; } pi;
    pi.h[0] = __floats2half2_rn(m0 - d0, m0 + d0);  // pos 2t: (lb, ub)
    pi.h[1] = __floats2half2_rn(m1 - d1, m1 + d1);  // pos 2t+1
    *(uint2*)(pxI + ob + 2 * t) = pi.u;
  }
}

// Recurrence (R11): gate-minor quad mapping, ONE barrier per step.
// 128 blocks: blockIdx<64 -> val LSTM for batch b; >=64 -> interval LSTM.
// Thread t = (unit n = t>>2, K-quarter q = t&3). Quad n computes the 4 gate
// rows {n, 256+n, 512+n, 768+n}: accumulators A0..A3 (gates) over quarter q,
// qsum4 butterfly -> every lane holds all 4 full gate sums (same per-row
// arithmetic/order as R9 -> bit-identical). Lane q applies gact to gate q
// only (px/bias are gate-minor: pos 4n+q = t, coalesced + prefetched); 4/8
// DPP quad-broadcasts distribute activated gates; cell update runs
// redundantly on all 16 waves. No sG, no second barrier, no serial tail.
// sH double-buffered (read buf, write buf^1, one barrier).
// W tiers: g=0,1,2 VGPR-pinned (96 regs, asm), g=3 LDS (128 KiB). Zero
// per-step global weight traffic (R10 showed streaming regresses).
__global__ __launch_bounds__(1024, 4)
void lstm_kernel(const uint4* __restrict__ P4, const __half* __restrict__ px,
                 float* __restrict__ out) {
  __shared__ uint4 sLW[8192];                       // 128 KiB: gate g=3
  __shared__ __align__(16) __half sH[2][2][4][72];  // [buf][comp][quarter][64+8 pad]
  const int t = threadIdx.x;
  const bool intv = blockIdx.x >= NB;
  const int b = intv ? blockIdx.x - NB : blockIdx.x;
  const int q = t & 3;
  const int n = t >> 2;
  // pinned W gates g=0,1,2 (96 VGPRs)
  uint4 Wp[3][8];
#pragma unroll
  for (int g = 0; g < 3; ++g)
#pragma unroll
    for (int c8 = 0; c8 < 8; ++c8)
      Wp[g][c8] = P4[((g * 8 + c8) << 10) + t];
#pragma unroll
  for (int g = 0; g < 3; ++g)
#pragma unroll
    for (int c8 = 0; c8 < 8; ++c8)
      asm volatile("" : "+v"(Wp[g][c8].x), "+v"(Wp[g][c8].y),
                        "+v"(Wp[g][c8].z), "+v"(Wp[g][c8].w));
  // stage g=3 into LDS (once; weights are step-invariant)
#pragma unroll
  for (int c8 = 0; c8 < 8; ++c8)
    sLW[(c8 << 10) + t] = P4[((24 + c8) << 10) + t];
  const bool is_tanh = (q == 2);                    // lane q owns gate q; gate 2 = g
  if (t < 576) ((unsigned*)sH)[t] = 0u;             // zero both buffers (2304 B)
  __syncthreads();
  float* outb = out + (size_t)b * NT * NH;
  int buf = 0;

  if (!intv) {
    // ---------------- point-value LSTM ----------------
    const __half* pxb = px + (size_t)b * NT * G4;
    float cv = 0.f;
    float pv = __half2float(pxb[t]);
    for (int ts = 0; ts < NT; ++ts) {
      const int tsn = (ts + 1 < NT) ? ts + 1 : ts;
      float nv = __half2float(pxb[(size_t)tsn * G4 + t]);   // prefetch
      float A0 = 0.f, A1 = 0.f, A2 = 0.f, A3 = 0.f;
#pragma unroll
      for (int c8 = 0; c8 < 8; ++c8) {
        uint4 wl3 = sLW[(c8 << 10) + t];                     // LDS g=3
        uint4 hv = *(const uint4*)(&sH[buf][0][q][c8 * 8]);  // quarter q
        accV(Wp[0][c8], hv, A0);
        accV(Wp[1][c8], hv, A1);
        accV(Wp[2][c8], hv, A2);
        accV(wl3, hv, A3);
      }
      A0 = qsum4(A0); A1 = qsum4(A1); A2 = qsum4(A2); A3 = qsum4(A3);
      float a = sel4(A0, A1, A2, A3, q);          // gate q of unit n
      float gt = gact(pv + a, is_tanh);           // bias pre-folded in px
      float ig = qb<0x00>(gt), fg = qb<0x55>(gt), gg = qb<0xAA>(gt), og = qb<0xFF>(gt);
      cv = fmaf(fg, cv, ig * gg);                 // redundant on all lanes
      float hvn = og * tanh_f(cv);
      if (q == 1) outb[(size_t)ts * NH + n] = hvn;
      if (q == 0) sH[buf ^ 1][0][n >> 6][n & 63] = __float2half(hvn);
      __syncthreads();
      buf ^= 1;
      pv = nv;
    }
  } else {
    // ---------------- interval (lb/ub) LSTM ----------------
    const __half2* pI = (const __half2*)(px + CSTRIDE) + (size_t)b * NT * G4;
    float cl = 0.f, cu = 0.f;
    __half2 plu = pI[t];
    for (int ts = 0; ts < NT; ++ts) {
      const int tsn = (ts + 1 < NT) ? ts + 1 : ts;
      __half2 nlu = pI[(size_t)tsn * G4 + t];     // prefetch
      float M0 = 0.f, M1 = 0.f, M2 = 0.f, M3 = 0.f;
      float R0 = 0.f, R1 = 0.f, R2 = 0.f, R3 = 0.f;
#pragma unroll
      for (int c8 = 0; c8 < 8; ++c8) {
        uint4 wl3 = sLW[(c8 << 10) + t];                     // LDS g=3
        uint4 hm = *(const uint4*)(&sH[buf][0][q][c8 * 8]);
        uint4 hr = *(const uint4*)(&sH[buf][1][q][c8 * 8]);
        accMR(Wp[0][c8], hm, hr, M0, R0);
        accMR(Wp[1][c8], hm, hr, M1, R1);
        accMR(Wp[2][c8], hm, hr, M2, R2);
        accMR(wl3, hm, hr, M3, R3);
      }
      M0 = qsum4(M0); M1 = qsum4(M1); M2 = qsum4(M2); M3 = qsum4(M3);
      R0 = qsum4(R0); R1 = qsum4(R1); R2 = qsum4(R2); R3 = qsum4(R3);
      float m = sel4(M0, M1, M2, M3, q);          // gate q of unit n
      float d = sel4(R0, R1, R2, R3, q);
      float pl = __low2float(plu), pu = __high2float(plu);  // bias pre-folded
      float gl = gact(pl + (m - d), is_tanh);
      float gu = gact(pu + (m + d), is_tanh);
      float il = qb<0x00>(gl), fl = qb<0x55>(gl), gl_ = qb<0xAA>(gl), ol = qb<0xFF>(gl);
      float iu = qb<0x00>(gu), fu = qb<0x55>(gu), gu_ = qb<0xAA>(gu), ou = qb<0xFF>(gu);
      // redundant on all lanes (deterministic -> all agree)
      float p0 = fl * cl, p1 = fl * cu, p2 = fu * cl, p3 = fu * cu;
      float fcl = min4c(p0, p1, p2, p3);
      float fcu = max4c(p0, p1, p2, p3);
      p0 = il * gl_; p1 = il * gu_; p2 = iu * gl_; p3 = iu * gu_;
      float igl = min4c(p0, p1, p2, p3);
      float igu = max4c(p0, p1, p2, p3);
      cl = fcl + igl; cu = fcu + igu;
      float tl = tanh_f(cl), tu = tanh_f(cu);
      p0 = ol * tl; p1 = ol * tu; p2 = ou * tl; p3 = ou * tu;
      float hl = min4c(p0, p1, p2, p3);
      float hu = max4c(p0, p1, p2, p3);
      if (q == 2) outb[OSTRIDE + (size_t)ts * NH + n] = hl;
      if (q == 3) outb[2 * OSTRIDE + (size_t)ts * NH + n] = hu;
      if (q == 0) sH[buf ^ 1][0][n >> 6][n & 63] = __float2half(0.5f * (hl + hu));
      if (q == 1) sH[buf ^ 1][1][n >> 6][n & 63] = __float2half(0.5f * (hu - hl));
      __syncthreads();
      buf ^= 1;
      plu = nlu;
    }
  }
}

extern "C" void kernel_launch(void* const* d_in, const int* in_sizes, int n_in,
                              void* d_out, int out_size, void* d_ws, size_t ws_size,
                              hipStream_t stream) {
  const float* xv   = (const float*)d_in[0];
  const float* xl   = (const float*)d_in[1];
  const float* xu   = (const float*)d_in[2];
  const float* Wih  = (const float*)d_in[3];
  const float* Whh  = (const float*)d_in[4];
  const float* bias = (const float*)d_in[5];
  float* out = (float*)d_out;
  char* ws = (char*)d_ws;
  uint4*  P4  = (uint4*)ws;                    // 512 KiB (recurrent W, gate-minor layout)
  uint4*  PIH = (uint4*)(ws + 512 * 1024);     // 256 KiB (px weights)
  __half* px  = (__half*)(ws + 768 * 1024);    // 192 MiB (val G4 + intv 2*G4 interleaved)

  conv_w_kernel<<<192, 256, 0, stream>>>(Whh, Wih, P4, PIH);
  px_kernel<<<NBT / 32, 512, 0, stream>>>(xv, xl, xu, PIH, bias, px);
  lstm_kernel<<<2 * NB, 1024, 0, stream>>>(P4, px, out);
}

// Round 8
// 2411.550 us; speedup vs baseline: 1.1333x; 1.1168x over previous
//
#include <hip/hip_runtime.h>
#include <hip/hip_fp16.h>

#define NB 64
#define NT 512
#define ND 128
#define NH 256
#define G4 1024                     // 4*H
#define NBT (NB*NT)                 // 32768
#define CSTRIDE ((size_t)NBT * G4)  // elements per interval component of px
#define OSTRIDE ((size_t)NBT * NH)  // elements per interval component of out

typedef _Float16 f16x2 __attribute__((ext_vector_type(2)));

__device__ __forceinline__ float fdot2u(unsigned a, unsigned b, float c) {
  return __builtin_amdgcn_fdot2(__builtin_bit_cast(f16x2, a),
                                __builtin_bit_cast(f16x2, b), c, false);
}

// val-only: 4 fdot2
__device__ __forceinline__ void accV(uint4 w, uint4 hv, float& av) {
  av = fdot2u(w.x, hv.x, av);
  av = fdot2u(w.y, hv.y, av);
  av = fdot2u(w.z, hv.z, av);
  av = fdot2u(w.w, hv.w, av);
}
// interval: mid += w.hm, rad += |w|.hr
__device__ __forceinline__ void accMR(uint4 w, uint4 hm, uint4 hr, float& am, float& ar) {
  const unsigned M = 0x7FFF7FFFu;
  am = fdot2u(w.x, hm.x, am); ar = fdot2u(w.x & M, hr.x, ar);
  am = fdot2u(w.y, hm.y, am); ar = fdot2u(w.y & M, hr.y, ar);
  am = fdot2u(w.z, hm.z, am); ar = fdot2u(w.z & M, hr.z, ar);
  am = fdot2u(w.w, hm.w, am); ar = fdot2u(w.w & M, hr.w, ar);
}

__device__ __forceinline__ float dpp_xor1(float x) {
  return __builtin_bit_cast(float,
      __builtin_amdgcn_update_dpp(0, __builtin_bit_cast(int, x), 0xB1, 0xF, 0xF, true));
}
__device__ __forceinline__ float dpp_xor2(float x) {
  return __builtin_bit_cast(float,
      __builtin_amdgcn_update_dpp(0, __builtin_bit_cast(int, x), 0x4E, 0xF, 0xF, true));
}
// R12 distributed 4-accumulator quad-reduce: lane q of each quad ends with the
// FULL sum of accumulator xq, tree ((q0+q1)+(q2+q3)) — bit-identical to the
// old qsum4(x)×4 + sel4 (differs only by FP-add commutativity, which is exact).
// 12 ops vs 19. Verified lane algebra:
//  round1: lane keeps its two owned-tier partials, receives partner's (xor 1)
//  round2: pair-sums exchanged across xor 2.
__device__ __forceinline__ float qred4(float x0, float x1, float x2, float x3, int q) {
  const bool b0 = (q & 1) != 0, b1 = (q & 2) != 0;
  float keepA = b0 ? x1 : x0, sendA = b0 ? x0 : x1;
  float QA = keepA + dpp_xor1(sendA);
  float keepB = b0 ? x3 : x2, sendB = b0 ? x2 : x3;
  float QB = keepB + dpp_xor1(sendB);
  float keep = b1 ? QB : QA, send = b1 ? QA : QB;
  return keep + dpp_xor2(send);
}

__device__ __forceinline__ float rcpf(float x) { return __builtin_amdgcn_rcpf(x); }
// R12 branchless gact: constants (sgn, fa, fb) hoisted per-thread outside the
// loop. tanh: fmaf(2,r,-1); sigmoid: fmaf(1,r,0) == r exactly (r>0).
__device__ __forceinline__ float gact_h(float x, float sgn, float fa, float fb) {
  float e = __expf(sgn * x);
  float r = rcpf(1.0f + e);
  return fmaf(fa, r, fb);
}
__device__ __forceinline__ float tanh_f(float x) {
  return fmaf(2.0f, rcpf(1.0f + __expf(-2.0f * x)), -1.0f);
}
// chain-shaped 4-way min/max -> v_min3/v_max3 fusion
__device__ __forceinline__ float min4c(float a, float b, float c, float d) {
  return fminf(fminf(fminf(a, b), c), d);
}
__device__ __forceinline__ float max4c(float a, float b, float c, float d) {
  return fmaxf(fmaxf(fmaxf(a, b), c), d);
}

// Pack weights f32->f16.  (R4 layout, verified)
// P4[(r*8+c8)*1024 + t] = Whh[j=(t>>2)*4 + r][k=(t&3)*64 + c8*8 ..+8], r=0..3
//   (R9 tiering: r=0,1,2 VGPR-pinned; r=3 LDS)
// PIH[(c*8+r)*512 + t]  = Wih[(t>>2)*8 + r][(t&3)*32 + c*8 ..+8]  (px kernel, verified R2-R4)
__global__ void conv_w_kernel(const float* __restrict__ Whh, const float* __restrict__ Wih,
                              uint4* __restrict__ P4, uint4* __restrict__ PIH) {
  int o = blockIdx.x * 256 + threadIdx.x;
  union { uint4 u; __half h[8]; } p;
  if (o < 32768) {
    int t = o & 1023, rc = o >> 10, r = rc >> 3, c8 = rc & 7;
    int j = ((t >> 2) << 2) + r, k = ((t & 3) << 6) + c8 * 8;
    const float* s = Whh + j * NH + k;
#pragma unroll
    for (int i = 0; i < 8; ++i) p.h[i] = __float2half(s[i]);
    P4[o] = p.u;
  } else if (o < 49152) {
    int o3 = o - 32768;
    int t = o3 & 511, rc = o3 >> 9, c = rc >> 3, r = rc & 7;
    int j = ((t >> 2) << 3) + r, k = ((t & 3) << 5) + c * 8;
    const float* s = Wih + j * ND + k;
#pragma unroll
    for (int i = 0; i < 8; ++i) p.h[i] = __float2half(s[i]);
    PIH[o3] = p.u;
  }
}

// px kernel: R2-R4 verified structure; R9 bias-fold + interleaved intv
// half2(lb,ub). R12: qsum4+sel4 -> qred4 (bit-identical tree).
// Lane t emits G4-rows 2t and 2t+1.
__global__ __launch_bounds__(512, 2)
void px_kernel(const float* __restrict__ xv, const float* __restrict__ xl,
               const float* __restrict__ xu, const uint4* __restrict__ PIH,
               const float* __restrict__ bias, __half* __restrict__ px) {
  __shared__ __align__(16) __half sv[32 * ND];
  __shared__ __align__(16) __half sm[32 * ND];
  __shared__ __align__(16) __half sr[32 * ND];
  const int t = threadIdx.x;
  const int q = t & 3;
  const int r0 = blockIdx.x * 32;
  const float b0 = bias[2 * t];
  const float b1 = bias[2 * t + 1];
  uint4 w[4][8];
#pragma unroll
  for (int c = 0; c < 4; ++c)
#pragma unroll
    for (int r = 0; r < 8; ++r)
      w[c][r] = PIH[((c * 8 + r) << 9) + t];
  {
    const float4* v4 = (const float4*)(xv + (size_t)r0 * ND);
    const float4* l4 = (const float4*)(xl + (size_t)r0 * ND);
    const float4* u4 = (const float4*)(xu + (size_t)r0 * ND);
    __half2* sv2 = (__half2*)sv; __half2* sm2 = (__half2*)sm; __half2* sr2 = (__half2*)sr;
    for (int i = t; i < 1024; i += 512) {
      float4 v = v4[i], l = l4[i], u = u4[i];
      sv2[2*i]   = __floats2half2_rn(v.x, v.y);
      sv2[2*i+1] = __floats2half2_rn(v.z, v.w);
      sm2[2*i]   = __floats2half2_rn(0.5f*(l.x+u.x), 0.5f*(l.y+u.y));
      sm2[2*i+1] = __floats2half2_rn(0.5f*(l.z+u.z), 0.5f*(l.w+u.w));
      sr2[2*i]   = __floats2half2_rn(0.5f*(u.x-l.x), 0.5f*(u.y-l.y));
      sr2[2*i+1] = __floats2half2_rn(0.5f*(u.z-l.z), 0.5f*(u.w-l.w));
    }
  }
  __syncthreads();
  const uint4* bv = (const uint4*)sv;
  const uint4* bm = (const uint4*)sm;
  const uint4* br = (const uint4*)sr;
  __half2* pxV = (__half2*)px;                    // val comp, half2 per 2 rows
  __half2* pxI = (__half2*)(px + CSTRIDE);        // intv comp, half2(lb,ub) per row
  for (int rr = 0; rr < 32; ++rr) {
    uint4 hv[4], hm[4], hr[4];
    const int base = rr * 16 + q * 4;
#pragma unroll
    for (int i = 0; i < 4; ++i) { hv[i] = bv[base+i]; hm[i] = bm[base+i]; hr[i] = br[base+i]; }
    float A[8][3];
#pragma unroll
    for (int r = 0; r < 8; ++r) { A[r][0] = 0.f; A[r][1] = 0.f; A[r][2] = 0.f; }
#pragma unroll
    for (int c = 0; c < 4; ++c)
#pragma unroll
      for (int r = 0; r < 8; ++r) {
        accV(w[c][r], hv[c], A[r][0]);
        accMR(w[c][r], hm[c], hr[c], A[r][1], A[r][2]);
      }
    // R12: distributed reduce — lane q gets row set {A[2q]} / {A[2q+... }
    // exactly as old qsum4-all + sel4(A0,A2,A4,A6 / A1,A3,A5,A7) did.
    float v0 = qred4(A[0][0], A[2][0], A[4][0], A[6][0], q) + b0;
    float m0 = qred4(A[0][1], A[2][1], A[4][1], A[6][1], q) + b0;
    float d0 = qred4(A[0][2], A[2][2], A[4][2], A[6][2], q);
    float v1 = qred4(A[1][0], A[3][0], A[5][0], A[7][0], q) + b1;
    float m1 = qred4(A[1][1], A[3][1], A[5][1], A[7][1], q) + b1;
    float d1 = qred4(A[1][2], A[3][2], A[5][2], A[7][2], q);
    size_t ob = (size_t)(r0 + rr) * G4;
    pxV[(ob >> 1) + t] = __floats2half2_rn(v0, v1);
    union { uint2 u; __half2 h[2]; } pi;
    pi.h[0] = __floats2half2_rn(m0 - d0, m0 + d0);  // row 2t: (lb, ub)
    pi.h[1] = __floats2half2_rn(m1 - d1, m1 + d1);  // row 2t+1
    *(uint2*)(pxI + ob + 2 * t) = pi.u;
  }
}

// Recurrence (R9 structure — best verified, 1932 µs; R12 = qred4 + hoisted
// gact constants ONLY, bit-identical math):
// 128 blocks: blockIdx<64 -> val LSTM for batch row b; >=64 -> interval LSTM.
// 1024 threads: q=t&3 K-quarter, 4 rows/thread (j = (t>>2)*4+r); after the
// distributed quad-reduce thread t owns gate row t exactly.
// W tiers: r=0,1,2 VGPR-pinned (96 regs, asm), r=3 in LDS (128 KiB, loaded
// once). ZERO per-step global weight traffic. px prefetched one step ahead
// (bias pre-folded; intv = one half2(lb,ub) load); out stores deferred one
// step. sG intv = float2(gl,gu).
__global__ __launch_bounds__(1024, 4)
void lstm_kernel(const uint4* __restrict__ P4, const __half* __restrict__ px,
                 float* __restrict__ out) {
  __shared__ uint4 sLW[8192];                     // 128 KiB: W row-index r=3
  __shared__ __align__(16) __half sH[2][4][72];   // [slot][q][64+8 pad]; val: slot0=hv; intv: 0=hm,1=hr
  __shared__ __align__(16) float sG[2][G4];       // val: sG[0][row]; intv: aliased as float2[row]=(gl,gu)
  float2* sGp = (float2*)sG;
  const int t = threadIdx.x;
  const bool intv = blockIdx.x >= NB;
  const int b = intv ? blockIdx.x - NB : blockIdx.x;
  const int q = t & 3;
  // pinned W rows r=0,1,2 (96 VGPRs)
  uint4 Wp[3][8];
#pragma unroll
  for (int r = 0; r < 3; ++r)
#pragma unroll
    for (int c8 = 0; c8 < 8; ++c8)
      Wp[r][c8] = P4[((r * 8 + c8) << 10) + t];
#pragma unroll
  for (int r = 0; r < 3; ++r)
#pragma unroll
    for (int c8 = 0; c8 < 8; ++c8)
      asm volatile("" : "+v"(Wp[r][c8].x), "+v"(Wp[r][c8].y),
                        "+v"(Wp[r][c8].z), "+v"(Wp[r][c8].w));
  // stage r=3 into LDS (once; weights are step-invariant)
#pragma unroll
  for (int c8 = 0; c8 < 8; ++c8)
    sLW[(c8 << 10) + t] = P4[((24 + c8) << 10) + t];
  const bool is_tanh = ((t >> 8) == 2);           // rows 512..767 = gate g
  // R12: hoisted gact constants (wave-uniform per thread)
  const float sgn = is_tanh ? -2.0f : -1.0f;
  const float fa  = is_tanh ?  2.0f :  1.0f;
  const float fb  = is_tanh ? -1.0f :  0.0f;
  if (t < 288) ((unsigned*)sH)[t] = 0u;           // zero h (1152 B)
  __syncthreads();
  float* outb = out + (size_t)b * NT * NH;

  if (!intv) {
    // ---------------- point-value LSTM ----------------
    const __half* pxb = px + (size_t)b * NT * G4;
    float cv = 0.f, hv_p = 0.f;
    float pv = __half2float(pxb[t]);
    for (int ts = 0; ts < NT; ++ts) {
      if (ts > 0 && t < NH) outb[(size_t)(ts - 1) * NH + t] = hv_p;
      const int tsn = (ts + 1 < NT) ? ts + 1 : ts;
      float nv = __half2float(pxb[(size_t)tsn * G4 + t]);
      float A0 = 0.f, A1 = 0.f, A2 = 0.f, A3 = 0.f;
#pragma unroll
      for (int c8 = 0; c8 < 8; ++c8) {
        uint4 wl3 = sLW[(c8 << 10) + t];                // LDS r=3
        uint4 hv = *(const uint4*)(&sH[0][q][c8 * 8]);  // quad-distinct broadcast
        accV(Wp[0][c8], hv, A0);
        accV(Wp[1][c8], hv, A1);
        accV(Wp[2][c8], hv, A2);
        accV(wl3, hv, A3);
      }
      float av = qred4(A0, A1, A2, A3, q);              // row t (distributed)
      float gt = gact_h(pv + av, sgn, fa, fb);          // bias pre-folded in px
      sG[0][t] = gt;
      __syncthreads();
      if (t < NH) {
        float iv = sG[0][t], fv = sG[0][NH + t], gv = sG[0][2 * NH + t], ov = sG[0][3 * NH + t];
        cv = fmaf(fv, cv, iv * gv);
        float hvn = ov * tanh_f(cv);
        hv_p = hvn;
        sH[0][t >> 6][t & 63] = __float2half(hvn);
      }
      __syncthreads();
      pv = nv;
    }
    if (t < NH) outb[(size_t)(NT - 1) * NH + t] = hv_p;
  } else {
    // ---------------- interval (lb/ub) LSTM ----------------
    const __half2* pI = (const __half2*)(px + CSTRIDE) + (size_t)b * NT * G4;
    float cl = 0.f, cu = 0.f, hl_p = 0.f, hu_p = 0.f;
    __half2 plu = pI[t];
    for (int ts = 0; ts < NT; ++ts) {
      if (ts > 0 && t < NH) {
        size_t o = (size_t)(ts - 1) * NH + t;
        outb[OSTRIDE + o] = hl_p; outb[2 * OSTRIDE + o] = hu_p;
      }
      const int tsn = (ts + 1 < NT) ? ts + 1 : ts;
      __half2 nlu = pI[(size_t)tsn * G4 + t];
      float M0 = 0.f, M1 = 0.f, M2 = 0.f, M3 = 0.f;
      float R0 = 0.f, R1 = 0.f, R2 = 0.f, R3 = 0.f;
#pragma unroll
      for (int c8 = 0; c8 < 8; ++c8) {
        uint4 wl3 = sLW[(c8 << 10) + t];                // LDS r=3
        uint4 hm = *(const uint4*)(&sH[0][q][c8 * 8]);
        uint4 hr = *(const uint4*)(&sH[1][q][c8 * 8]);
        accMR(Wp[0][c8], hm, hr, M0, R0);
        accMR(Wp[1][c8], hm, hr, M1, R1);
        accMR(Wp[2][c8], hm, hr, M2, R2);
        accMR(wl3, hm, hr, M3, R3);
      }
      float m = qred4(M0, M1, M2, M3, q);               // row t (distributed)
      float d = qred4(R0, R1, R2, R3, q);
      float pl = __low2float(plu), pu = __high2float(plu);  // bias pre-folded
      float gl = gact_h(pl + (m - d), sgn, fa, fb);
      float gu = gact_h(pu + (m + d), sgn, fa, fb);
      sGp[t] = make_float2(gl, gu);                     // one b64 write
      __syncthreads();
      if (t < NH) {
        float2 gi = sGp[t], gf = sGp[NH + t], gg = sGp[2 * NH + t], go = sGp[3 * NH + t];
        float il = gi.x, iu = gi.y, fl = gf.x, fu = gf.y;
        float gl_ = gg.x, gu_ = gg.y, ol = go.x, ou = go.y;
        float p0 = fl*cl, p1 = fl*cu, p2 = fu*cl, p3 = fu*cu;
        float fcl = min4c(p0, p1, p2, p3);
        float fcu = max4c(p0, p1, p2, p3);
        p0 = il*gl_; p1 = il*gu_; p2 = iu*gl_; p3 = iu*gu_;
        float igl = min4c(p0, p1, p2, p3);
        float igu = max4c(p0, p1, p2, p3);
        cl = fcl + igl; cu = fcu + igu;
        float tl = tanh_f(cl), tu = tanh_f(cu);
        p0 = ol*tl; p1 = ol*tu; p2 = ou*tl; p3 = ou*tu;
        float hl = min4c(p0, p1, p2, p3);
        float hu = max4c(p0, p1, p2, p3);
        hl_p = hl; hu_p = hu;
        sH[0][t >> 6][t & 63] = __float2half(0.5f * (hl + hu));
        sH[1][t >> 6][t & 63] = __float2half(0.5f * (hu - hl));
      }
      __syncthreads();
      plu = nlu;
    }
    if (t < NH) {
      size_t o = (size_t)(NT - 1) * NH + t;
      outb[OSTRIDE + o] = hl_p; outb[2 * OSTRIDE + o] = hu_p;
    }
  }
}

extern "C" void kernel_launch(void* const* d_in, const int* in_sizes, int n_in,
                              void* d_out, int out_size, void* d_ws, size_t ws_size,
                              hipStream_t stream) {
  const float* xv   = (const float*)d_in[0];
  const float* xl   = (const float*)d_in[1];
  const float* xu   = (const float*)d_in[2];
  const float* Wih  = (const float*)d_in[3];
  const float* Whh  = (const float*)d_in[4];
  const float* bias = (const float*)d_in[5];
  float* out = (float*)d_out;
  char* ws = (char*)d_ws;
  uint4*  P4  = (uint4*)ws;                    // 512 KiB (recurrent W, 4-row layout)
  uint4*  PIH = (uint4*)(ws + 512 * 1024);     // 256 KiB (px weights)
  __half* px  = (__half*)(ws + 768 * 1024);    // 192 MiB (val G4 + intv 2*G4 interleaved)

  conv_w_kernel<<<192, 256, 0, stream>>>(Whh, Wih, P4, PIH);
  px_kernel<<<NBT / 32, 512, 0, stream>>>(xv, xl, xu, PIH, bias, px);
  lstm_kernel<<<2 * NB, 1024, 0, stream>>>(P4, px, out);
}

// Round 9
// 2289.634 us; speedup vs baseline: 1.1936x; 1.0532x over previous
//
#include <hip/hip_runtime.h>
#include <hip/hip_fp16.h>

#define NB 64
#define NT 512
#define ND 128
#define NH 256
#define G4 1024                     // 4*H
#define NBT (NB*NT)                 // 32768
#define CSTRIDE ((size_t)NBT * G4)  // elements per interval component of px
#define OSTRIDE ((size_t)NBT * NH)  // elements per interval component of out

typedef _Float16 f16x2 __attribute__((ext_vector_type(2)));

__device__ __forceinline__ float fdot2u(unsigned a, unsigned b, float c) {
  return __builtin_amdgcn_fdot2(__builtin_bit_cast(f16x2, a),
                                __builtin_bit_cast(f16x2, b), c, false);
}

// val-only: 4 fdot2
__device__ __forceinline__ void accV(uint4 w, uint4 hv, float& av) {
  av = fdot2u(w.x, hv.x, av);
  av = fdot2u(w.y, hv.y, av);
  av = fdot2u(w.z, hv.z, av);
  av = fdot2u(w.w, hv.w, av);
}
// interval: mid += w.hm, rad += |w|.hr
__device__ __forceinline__ void accMR(uint4 w, uint4 hm, uint4 hr, float& am, float& ar) {
  const unsigned M = 0x7FFF7FFFu;
  am = fdot2u(w.x, hm.x, am); ar = fdot2u(w.x & M, hr.x, ar);
  am = fdot2u(w.y, hm.y, am); ar = fdot2u(w.y & M, hr.y, ar);
  am = fdot2u(w.z, hm.z, am); ar = fdot2u(w.z & M, hr.z, ar);
  am = fdot2u(w.w, hm.w, am); ar = fdot2u(w.w & M, hr.w, ar);
}

// quad all-reduce via DPP quad_perm (verified R2-R4). 8 independent instances
// per intv step — their DPP->VALU hazard stalls hide under each other.
// (R12's "cheaper" distributed reduce serialized these chains and LOST 130µs:
// this loop is dependency-latency-bound, not issue-bound. Do not re-shape.)
__device__ __forceinline__ float qsum4(float x) {
  int v = __builtin_amdgcn_update_dpp(0, __builtin_bit_cast(int, x), 0xB1, 0xF, 0xF, true);
  x += __builtin_bit_cast(float, v);
  v = __builtin_amdgcn_update_dpp(0, __builtin_bit_cast(int, x), 0x4E, 0xF, 0xF, true);
  x += __builtin_bit_cast(float, v);
  return x;
}
__device__ __forceinline__ float sel4(float x0, float x1, float x2, float x3, int q) {
  float a = (q & 1) ? x1 : x0;
  float b = (q & 1) ? x3 : x2;
  return (q & 2) ? b : a;
}

__device__ __forceinline__ float rcpf(float x) { return __builtin_amdgcn_rcpf(x); }
__device__ __forceinline__ float gact(float x, bool is_tanh) {
  float s = is_tanh ? -2.0f : -1.0f;
  float e = __expf(s * x);
  float r = rcpf(1.0f + e);
  return is_tanh ? fmaf(2.0f, r, -1.0f) : r;
}
__device__ __forceinline__ float tanh_f(float x) {
  return fmaf(2.0f, rcpf(1.0f + __expf(-2.0f * x)), -1.0f);
}
// chain-shaped 4-way min/max -> v_min3/v_max3 fusion (2 ops instead of 3)
__device__ __forceinline__ float min4c(float a, float b, float c, float d) {
  return fminf(fminf(fminf(a, b), c), d);
}
__device__ __forceinline__ float max4c(float a, float b, float c, float d) {
  return fmaxf(fmaxf(fmaxf(a, b), c), d);
}

// Pack weights f32->f16.  (R4 layout, verified)
// P4[(r*8+c8)*1024 + t] = Whh[j=(t>>2)*4 + r][k=(t&3)*64 + c8*8 ..+8], r=0..3
//   (R9 tiering: r=0,1,2 VGPR-pinned; r=3 LDS)
// PIH[(c*8+r)*512 + t]  = Wih[(t>>2)*8 + r][(t&3)*32 + c*8 ..+8]  (px kernel, verified R2-R4)
__global__ void conv_w_kernel(const float* __restrict__ Whh, const float* __restrict__ Wih,
                              uint4* __restrict__ P4, uint4* __restrict__ PIH) {
  int o = blockIdx.x * 256 + threadIdx.x;
  union { uint4 u; __half h[8]; } p;
  if (o < 32768) {
    int t = o & 1023, rc = o >> 10, r = rc >> 3, c8 = rc & 7;
    int j = ((t >> 2) << 2) + r, k = ((t & 3) << 6) + c8 * 8;
    const float* s = Whh + j * NH + k;
#pragma unroll
    for (int i = 0; i < 8; ++i) p.h[i] = __float2half(s[i]);
    P4[o] = p.u;
  } else if (o < 49152) {
    int o3 = o - 32768;
    int t = o3 & 511, rc = o3 >> 9, c = rc >> 3, r = rc & 7;
    int j = ((t >> 2) << 3) + r, k = ((t & 3) << 5) + c * 8;
    const float* s = Wih + j * ND + k;
#pragma unroll
    for (int i = 0; i < 8; ++i) p.h[i] = __float2half(s[i]);
    PIH[o3] = p.u;
  }
}

// px kernel: R2-R4 verified structure. R9: bias folded in (b0/b1 per emitted
// row), intv components stored INTERLEAVED as half2(lb,ub) per row at CSTRIDE.
// Lane t emits G4-rows 2t and 2t+1 (j0=2t, j1=2t+1; verified mapping).
__global__ __launch_bounds__(512, 2)
void px_kernel(const float* __restrict__ xv, const float* __restrict__ xl,
               const float* __restrict__ xu, const uint4* __restrict__ PIH,
               const float* __restrict__ bias, __half* __restrict__ px) {
  __shared__ __align__(16) __half sv[32 * ND];
  __shared__ __align__(16) __half sm[32 * ND];
  __shared__ __align__(16) __half sr[32 * ND];
  const int t = threadIdx.x;
  const int q = t & 3;
  const int r0 = blockIdx.x * 32;
  const float b0 = bias[2 * t];
  const float b1 = bias[2 * t + 1];
  uint4 w[4][8];
#pragma unroll
  for (int c = 0; c < 4; ++c)
#pragma unroll
    for (int r = 0; r < 8; ++r)
      w[c][r] = PIH[((c * 8 + r) << 9) + t];
  {
    const float4* v4 = (const float4*)(xv + (size_t)r0 * ND);
    const float4* l4 = (const float4*)(xl + (size_t)r0 * ND);
    const float4* u4 = (const float4*)(xu + (size_t)r0 * ND);
    __half2* sv2 = (__half2*)sv; __half2* sm2 = (__half2*)sm; __half2* sr2 = (__half2*)sr;
    for (int i = t; i < 1024; i += 512) {
      float4 v = v4[i], l = l4[i], u = u4[i];
      sv2[2*i]   = __floats2half2_rn(v.x, v.y);
      sv2[2*i+1] = __floats2half2_rn(v.z, v.w);
      sm2[2*i]   = __floats2half2_rn(0.5f*(l.x+u.x), 0.5f*(l.y+u.y));
      sm2[2*i+1] = __floats2half2_rn(0.5f*(l.z+u.z), 0.5f*(l.w+u.w));
      sr2[2*i]   = __floats2half2_rn(0.5f*(u.x-l.x), 0.5f*(u.y-l.y));
      sr2[2*i+1] = __floats2half2_rn(0.5f*(u.z-l.z), 0.5f*(u.w-l.w));
    }
  }
  __syncthreads();
  const uint4* bv = (const uint4*)sv;
  const uint4* bm = (const uint4*)sm;
  const uint4* br = (const uint4*)sr;
  __half2* pxV = (__half2*)px;                    // val comp, half2 per 2 rows
  __half2* pxI = (__half2*)(px + CSTRIDE);        // intv comp, half2(lb,ub) per row
  for (int rr = 0; rr < 32; ++rr) {
    uint4 hv[4], hm[4], hr[4];
    const int base = rr * 16 + q * 4;
#pragma unroll
    for (int i = 0; i < 4; ++i) { hv[i] = bv[base+i]; hm[i] = bm[base+i]; hr[i] = br[base+i]; }
    float A[8][3];
#pragma unroll
    for (int r = 0; r < 8; ++r) { A[r][0] = 0.f; A[r][1] = 0.f; A[r][2] = 0.f; }
#pragma unroll
    for (int c = 0; c < 4; ++c)
#pragma unroll
      for (int r = 0; r < 8; ++r) {
        accV(w[c][r], hv[c], A[r][0]);
        accMR(w[c][r], hm[c], hr[c], A[r][1], A[r][2]);
      }
#pragma unroll
    for (int r = 0; r < 8; ++r) {
      A[r][0] = qsum4(A[r][0]); A[r][1] = qsum4(A[r][1]); A[r][2] = qsum4(A[r][2]);
    }
    float v0 = sel4(A[0][0], A[2][0], A[4][0], A[6][0], q) + b0;
    float m0 = sel4(A[0][1], A[2][1], A[4][1], A[6][1], q) + b0;
    float d0 = sel4(A[0][2], A[2][2], A[4][2], A[6][2], q);
    float v1 = sel4(A[1][0], A[3][0], A[5][0], A[7][0], q) + b1;
    float m1 = sel4(A[1][1], A[3][1], A[5][1], A[7][1], q) + b1;
    float d1 = sel4(A[1][2], A[3][2], A[5][2], A[7][2], q);
    size_t ob = (size_t)(r0 + rr) * G4;
    pxV[(ob >> 1) + t] = __floats2half2_rn(v0, v1);
    union { uint2 u; __half2 h[2]; } pi;
    pi.h[0] = __floats2half2_rn(m0 - d0, m0 + d0);  // row 2t: (lb, ub)
    pi.h[1] = __floats2half2_rn(m1 - d1, m1 + d1);  // row 2t+1
    *(uint2*)(pxI + ob + 2 * t) = pi.u;
  }
}

// Recurrence (R9 = best verified configuration, 1932 µs lstm / 2278 total):
// 128 blocks: blockIdx<64 -> val LSTM for batch row b; >=64 -> interval LSTM.
// 1024 threads: q=t&3 K-quarter, 4 rows/thread (j = (t>>2)*4+r); after quad
// reduce+sel4 thread t owns gate row t exactly.
// W tiers: r=0,1,2 VGPR-pinned (96 regs, asm), r=3 in LDS (128 KiB, loaded
// once). ZERO per-step global weight traffic (R10: streaming regresses).
// px prefetched one step ahead (bias pre-folded; intv = one half2(lb,ub)
// load); out stores deferred one step. sG intv = float2(gl,gu).
// Two-barrier skeleton is the verified optimum of this family: R5/R7/R11
// one-barrier variants all regressed (lockstep serial tail); R8 LDS-only
// barriers neutral; R12 chain-shortened reduce regressed (DPP chain depth).
__global__ __launch_bounds__(1024, 4)
void lstm_kernel(const uint4* __restrict__ P4, const __half* __restrict__ px,
                 float* __restrict__ out) {
  __shared__ uint4 sLW[8192];                     // 128 KiB: W row-index r=3
  __shared__ __align__(16) __half sH[2][4][72];   // [slot][q][64+8 pad]; val: slot0=hv; intv: 0=hm,1=hr
  __shared__ __align__(16) float sG[2][G4];       // val: sG[0][row]; intv: aliased as float2[row]=(gl,gu)
  float2* sGp = (float2*)sG;
  const int t = threadIdx.x;
  const bool intv = blockIdx.x >= NB;
  const int b = intv ? blockIdx.x - NB : blockIdx.x;
  const int q = t & 3;
  // pinned W rows r=0,1,2 (96 VGPRs)
  uint4 Wp[3][8];
#pragma unroll
  for (int r = 0; r < 3; ++r)
#pragma unroll
    for (int c8 = 0; c8 < 8; ++c8)
      Wp[r][c8] = P4[((r * 8 + c8) << 10) + t];
#pragma unroll
  for (int r = 0; r < 3; ++r)
#pragma unroll
    for (int c8 = 0; c8 < 8; ++c8)
      asm volatile("" : "+v"(Wp[r][c8].x), "+v"(Wp[r][c8].y),
                        "+v"(Wp[r][c8].z), "+v"(Wp[r][c8].w));
  // stage r=3 into LDS (once; weights are step-invariant)
#pragma unroll
  for (int c8 = 0; c8 < 8; ++c8)
    sLW[(c8 << 10) + t] = P4[((24 + c8) << 10) + t];
  const bool is_tanh = ((t >> 8) == 2);           // rows 512..767 = gate g
  if (t < 288) ((unsigned*)sH)[t] = 0u;           // zero h (1152 B)
  __syncthreads();
  float* outb = out + (size_t)b * NT * NH;

  if (!intv) {
    // ---------------- point-value LSTM ----------------
    const __half* pxb = px + (size_t)b * NT * G4;
    float cv = 0.f, hv_p = 0.f;
    float pv = __half2float(pxb[t]);
    for (int ts = 0; ts < NT; ++ts) {
      if (ts > 0 && t < NH) outb[(size_t)(ts - 1) * NH + t] = hv_p;
      const int tsn = (ts + 1 < NT) ? ts + 1 : ts;
      float nv = __half2float(pxb[(size_t)tsn * G4 + t]);
      float A0 = 0.f, A1 = 0.f, A2 = 0.f, A3 = 0.f;
#pragma unroll
      for (int c8 = 0; c8 < 8; ++c8) {
        uint4 wl3 = sLW[(c8 << 10) + t];                // LDS r=3
        uint4 hv = *(const uint4*)(&sH[0][q][c8 * 8]);  // quad-distinct broadcast
        accV(Wp[0][c8], hv, A0);
        accV(Wp[1][c8], hv, A1);
        accV(Wp[2][c8], hv, A2);
        accV(wl3, hv, A3);
      }
      A0 = qsum4(A0); A1 = qsum4(A1); A2 = qsum4(A2); A3 = qsum4(A3);
      float av = sel4(A0, A1, A2, A3, q);               // row t
      float gt = gact(pv + av, is_tanh);                // bias pre-folded in px
      sG[0][t] = gt;
      __syncthreads();
      if (t < NH) {
        float iv = sG[0][t], fv = sG[0][NH + t], gv = sG[0][2 * NH + t], ov = sG[0][3 * NH + t];
        cv = fmaf(fv, cv, iv * gv);
        float hvn = ov * tanh_f(cv);
        hv_p = hvn;
        sH[0][t >> 6][t & 63] = __float2half(hvn);
      }
      __syncthreads();
      pv = nv;
    }
    if (t < NH) outb[(size_t)(NT - 1) * NH + t] = hv_p;
  } else {
    // ---------------- interval (lb/ub) LSTM ----------------
    const __half2* pI = (const __half2*)(px + CSTRIDE) + (size_t)b * NT * G4;
    float cl = 0.f, cu = 0.f, hl_p = 0.f, hu_p = 0.f;
    __half2 plu = pI[t];
    for (int ts = 0; ts < NT; ++ts) {
      if (ts > 0 && t < NH) {
        size_t o = (size_t)(ts - 1) * NH + t;
        outb[OSTRIDE + o] = hl_p; outb[2 * OSTRIDE + o] = hu_p;
      }
      const int tsn = (ts + 1 < NT) ? ts + 1 : ts;
      __half2 nlu = pI[(size_t)tsn * G4 + t];
      float M0 = 0.f, M1 = 0.f, M2 = 0.f, M3 = 0.f;
      float R0 = 0.f, R1 = 0.f, R2 = 0.f, R3 = 0.f;
#pragma unroll
      for (int c8 = 0; c8 < 8; ++c8) {
        uint4 wl3 = sLW[(c8 << 10) + t];                // LDS r=3
        uint4 hm = *(const uint4*)(&sH[0][q][c8 * 8]);
        uint4 hr = *(const uint4*)(&sH[1][q][c8 * 8]);
        accMR(Wp[0][c8], hm, hr, M0, R0);
        accMR(Wp[1][c8], hm, hr, M1, R1);
        accMR(Wp[2][c8], hm, hr, M2, R2);
        accMR(wl3, hm, hr, M3, R3);
      }
      M0 = qsum4(M0); M1 = qsum4(M1); M2 = qsum4(M2); M3 = qsum4(M3);
      R0 = qsum4(R0); R1 = qsum4(R1); R2 = qsum4(R2); R3 = qsum4(R3);
      float m = sel4(M0, M1, M2, M3, q);                // row t
      float d = sel4(R0, R1, R2, R3, q);
      float pl = __low2float(plu), pu = __high2float(plu);  // bias pre-folded
      float gl = gact(pl + (m - d), is_tanh);
      float gu = gact(pu + (m + d), is_tanh);
      sGp[t] = make_float2(gl, gu);                     // one b64 write
      __syncthreads();
      if (t < NH) {
        float2 gi = sGp[t], gf = sGp[NH + t], gg = sGp[2 * NH + t], go = sGp[3 * NH + t];
        float il = gi.x, iu = gi.y, fl = gf.x, fu = gf.y;
        float gl_ = gg.x, gu_ = gg.y, ol = go.x, ou = go.y;
        float p0 = fl*cl, p1 = fl*cu, p2 = fu*cl, p3 = fu*cu;
        float fcl = min4c(p0, p1, p2, p3);
        float fcu = max4c(p0, p1, p2, p3);
        p0 = il*gl_; p1 = il*gu_; p2 = iu*gl_; p3 = iu*gu_;
        float igl = min4c(p0, p1, p2, p3);
        float igu = max4c(p0, p1, p2, p3);
        cl = fcl + igl; cu = fcu + igu;
        float tl = tanh_f(cl), tu = tanh_f(cu);
        p0 = ol*tl; p1 = ol*tu; p2 = ou*tl; p3 = ou*tu;
        float hl = min4c(p0, p1, p2, p3);
        float hu = max4c(p0, p1, p2, p3);
        hl_p = hl; hu_p = hu;
        sH[0][t >> 6][t & 63] = __float2half(0.5f * (hl + hu));
        sH[1][t >> 6][t & 63] = __float2half(0.5f * (hu - hl));
      }
      __syncthreads();
      plu = nlu;
    }
    if (t < NH) {
      size_t o = (size_t)(NT - 1) * NH + t;
      outb[OSTRIDE + o] = hl_p; outb[2 * OSTRIDE + o] = hu_p;
    }
  }
}

extern "C" void kernel_launch(void* const* d_in, const int* in_sizes, int n_in,
                              void* d_out, int out_size, void* d_ws, size_t ws_size,
                              hipStream_t stream) {
  const float* xv   = (const float*)d_in[0];
  const float* xl   = (const float*)d_in[1];
  const float* xu   = (const float*)d_in[2];
  const float* Wih  = (const float*)d_in[3];
  const float* Whh  = (const float*)d_in[4];
  const float* bias = (const float*)d_in[5];
  float* out = (float*)d_out;
  char* ws = (char*)d_ws;
  uint4*  P4  = (uint4*)ws;                    // 512 KiB (recurrent W, 4-row layout)
  uint4*  PIH = (uint4*)(ws + 512 * 1024);     // 256 KiB (px weights)
  __half* px  = (__half*)(ws + 768 * 1024);    // 192 MiB (val G4 + intv 2*G4 interleaved)

  conv_w_kernel<<<192, 256, 0, stream>>>(Whh, Wih, P4, PIH);
  px_kernel<<<NBT / 32, 512, 0, stream>>>(xv, xl, xu, PIH, bias, px);
  lstm_kernel<<<2 * NB, 1024, 0, stream>>>(P4, px, out);
}

// Round 10
// 2047.966 us; speedup vs baseline: 1.3344x; 1.1180x over previous
//
#include <hip/hip_runtime.h>
#include <hip/hip_fp16.h>

#define NB 64
#define NT 512
#define ND 128
#define NH 256
#define G4 1024                     // 4*H
#define NBT (NB*NT)                 // 32768
#define CSTRIDE ((size_t)NBT * G4)  // elements per interval component of px
#define OSTRIDE ((size_t)NBT * NH)  // elements per interval component of out

typedef _Float16 f16x2 __attribute__((ext_vector_type(2)));
typedef _Float16 f16x4 __attribute__((ext_vector_type(4)));
typedef float f32x4 __attribute__((ext_vector_type(4)));

__device__ __forceinline__ float fdot2u(unsigned a, unsigned b, float c) {
  return __builtin_amdgcn_fdot2(__builtin_bit_cast(f16x2, a),
                                __builtin_bit_cast(f16x2, b), c, false);
}

// val-only: 4 fdot2
__device__ __forceinline__ void accV(uint4 w, uint4 hv, float& av) {
  av = fdot2u(w.x, hv.x, av);
  av = fdot2u(w.y, hv.y, av);
  av = fdot2u(w.z, hv.z, av);
  av = fdot2u(w.w, hv.w, av);
}
// interval: mid += w.hm, rad += |w|.hr
__device__ __forceinline__ void accMR(uint4 w, uint4 hm, uint4 hr, float& am, float& ar) {
  const unsigned M = 0x7FFF7FFFu;
  am = fdot2u(w.x, hm.x, am); ar = fdot2u(w.x & M, hr.x, ar);
  am = fdot2u(w.y, hm.y, am); ar = fdot2u(w.y & M, hr.y, ar);
  am = fdot2u(w.z, hm.z, am); ar = fdot2u(w.z & M, hr.z, ar);
  am = fdot2u(w.w, hm.w, am); ar = fdot2u(w.w & M, hr.w, ar);
}

// quad all-reduce via DPP quad_perm (verified R2-R4). 8 independent instances
// per intv step — their DPP->VALU hazard stalls hide under each other.
__device__ __forceinline__ float qsum4(float x) {
  int v = __builtin_amdgcn_update_dpp(0, __builtin_bit_cast(int, x), 0xB1, 0xF, 0xF, true);
  x += __builtin_bit_cast(float, v);
  v = __builtin_amdgcn_update_dpp(0, __builtin_bit_cast(int, x), 0x4E, 0xF, 0xF, true);
  x += __builtin_bit_cast(float, v);
  return x;
}
__device__ __forceinline__ float sel4(float x0, float x1, float x2, float x3, int q) {
  float a = (q & 1) ? x1 : x0;
  float b = (q & 1) ? x3 : x2;
  return (q & 2) ? b : a;
}

__device__ __forceinline__ float rcpf(float x) { return __builtin_amdgcn_rcpf(x); }
__device__ __forceinline__ float gact(float x, bool is_tanh) {
  float s = is_tanh ? -2.0f : -1.0f;
  float e = __expf(s * x);
  float r = rcpf(1.0f + e);
  return is_tanh ? fmaf(2.0f, r, -1.0f) : r;
}
__device__ __forceinline__ float tanh_f(float x) {
  return fmaf(2.0f, rcpf(1.0f + __expf(-2.0f * x)), -1.0f);
}
// chain-shaped 4-way min/max -> v_min3/v_max3 fusion (2 ops instead of 3)
__device__ __forceinline__ float min4c(float a, float b, float c, float d) {
  return fminf(fminf(fminf(a, b), c), d);
}
__device__ __forceinline__ float max4c(float a, float b, float c, float d) {
  return fmaxf(fmaxf(fmaxf(a, b), c), d);
}

__device__ __forceinline__ f16x4 h4(unsigned a, unsigned b) {
  uint2 u = make_uint2(a, b);
  return __builtin_bit_cast(f16x4, u);
}

// Pack weights f32->f16.
// P4 (lstm, R4 layout, verified — UNCHANGED):
//   P4[(r*8+c8)*1024 + t] = Whh[j=(t>>2)*4 + r][k=(t&3)*64 + c8*8 ..+8], r=0..3
// PB (R14, px MFMA B-fragments, 16384 uint4 = 256 KiB in PIH's old slot):
//   for nt=0..63 (N-tile), kp=0..3 (K-step pair), l=0..63 (lane):
//   PB[(nt*4+kp)*64 + l]: h[e]   = Wih[nt*16+(l&15)][kp*32 + 4*(l>>4) + e]
//                         h[4+e] = Wih[nt*16+(l&15)][kp*32 + 16 + 4*(l>>4) + e]
//   = B-fragment of v_mfma_f32_16x16x16f16 for ks=2kp (lo) / 2kp+1 (hi):
//     B[k][j]: j = lane%16, k = ks*16 + 4*(lane/16) + e.
__global__ void conv_w_kernel(const float* __restrict__ Whh, const float* __restrict__ Wih,
                              uint4* __restrict__ P4, uint4* __restrict__ PB) {
  int o = blockIdx.x * 256 + threadIdx.x;
  union { uint4 u; __half h[8]; } p;
  if (o < 32768) {
    int t = o & 1023, rc = o >> 10, r = rc >> 3, c8 = rc & 7;
    int j = ((t >> 2) << 2) + r, k = ((t & 3) << 6) + c8 * 8;
    const float* s = Whh + j * NH + k;
#pragma unroll
    for (int i = 0; i < 8; ++i) p.h[i] = __float2half(s[i]);
    P4[o] = p.u;
  } else if (o < 49152) {
    int o3 = o - 32768;                       // 0..16383
    int l = o3 & 63, rest = o3 >> 6;
    int kp = rest & 3, nt = rest >> 2;        // nt 0..63
    int j = nt * 16 + (l & 15);
    int k0 = kp * 32 + ((l >> 4) << 2);
    const float* s = Wih + j * ND + k0;
#pragma unroll
    for (int i = 0; i < 4; ++i) { p.h[i] = __float2half(s[i]); p.h[4 + i] = __float2half(s[16 + i]); }
    PB[o3] = p.u;
  }
}

// px via MFMA (R14). 3 GEMMs C[r][j] = X[r][:]·Wih[j][:] for X ∈ {val, mid,
// rad(|W|)}; M=32768, N=1024, K=128. v_mfma_f32_16x16x16f16, 8 K-steps on one
// accumulator (guide K-loop recipe). Fragment layouts (classic CDNA, C/D
// HW-verified m89): A row=lane%16 k=4*(lane/16)+e; B col=lane%16 same k;
// C/D col=lane&15 row=4*(lane>>4)+e.
// Per wave: one 16-row M-tile; A-frags built once from xv/xl/xu (same rn f16
// conversions as the old px staging); loop 64 N-tiles: 4 coalesced PB loads,
// |W| via &0x7FFF7FFF (== old accMR), 24 MFMA, bias-fold epilogue, stores in
// the EXACT R9 px layout (val half @ px[r*1024+j]; intv half2(lb,ub) @
// (px+CSTRIDE)[r*1024+j]) -> lstm_kernel unchanged.
__global__ __launch_bounds__(256, 2)
void px_mfma(const float* __restrict__ xv, const float* __restrict__ xl,
             const float* __restrict__ xu, const uint4* __restrict__ PB,
             const float* __restrict__ bias, __half* __restrict__ px) {
  const int l = threadIdx.x & 63;
  const int w = threadIdx.x >> 6;             // wave 0..3
  const int rt = blockIdx.x * 64 + w * 16;    // M-tile base row
  const int li = l & 15, g = l >> 4;
  const unsigned M = 0x7FFF7FFFu;
  // ---- A fragments (once per wave): rows rt..rt+15, K=128 in 8 steps ----
  f16x4 av[8], am[8], ar[8];
  {
    const int row = rt + li;
    const float* pv = xv + (size_t)row * ND + g * 4;
    const float* pl = xl + (size_t)row * ND + g * 4;
    const float* pu = xu + (size_t)row * ND + g * 4;
#pragma unroll
    for (int ks = 0; ks < 8; ++ks) {
      float4 vv = *(const float4*)(pv + ks * 16);
      float4 ll = *(const float4*)(pl + ks * 16);
      float4 uu = *(const float4*)(pu + ks * 16);
      av[ks][0] = (_Float16)vv.x; av[ks][1] = (_Float16)vv.y;
      av[ks][2] = (_Float16)vv.z; av[ks][3] = (_Float16)vv.w;
      am[ks][0] = (_Float16)(0.5f * (ll.x + uu.x)); am[ks][1] = (_Float16)(0.5f * (ll.y + uu.y));
      am[ks][2] = (_Float16)(0.5f * (ll.z + uu.z)); am[ks][3] = (_Float16)(0.5f * (ll.w + uu.w));
      ar[ks][0] = (_Float16)(0.5f * (uu.x - ll.x)); ar[ks][1] = (_Float16)(0.5f * (uu.y - ll.y));
      ar[ks][2] = (_Float16)(0.5f * (uu.z - ll.z)); ar[ks][3] = (_Float16)(0.5f * (uu.w - ll.w));
    }
  }
  __half*  pxV = px;
  __half2* pxI = (__half2*)(px + CSTRIDE);
  // ---- N-tile loop ----
  for (int nt = 0; nt < 64; ++nt) {
    uint4 B0 = PB[(nt * 4 + 0) * 64 + l];
    uint4 B1 = PB[(nt * 4 + 1) * 64 + l];
    uint4 B2 = PB[(nt * 4 + 2) * 64 + l];
    uint4 B3 = PB[(nt * 4 + 3) * 64 + l];
    f32x4 accv = {0.f, 0.f, 0.f, 0.f};
    f32x4 accm = {0.f, 0.f, 0.f, 0.f};
    f32x4 accr = {0.f, 0.f, 0.f, 0.f};
#pragma unroll
    for (int kp = 0; kp < 4; ++kp) {
      uint4 B = (kp == 0) ? B0 : (kp == 1) ? B1 : (kp == 2) ? B2 : B3;
      f16x4 blo = h4(B.x, B.y);
      f16x4 bhi = h4(B.z, B.w);
      f16x4 alo = h4(B.x & M, B.y & M);
      f16x4 ahi = h4(B.z & M, B.w & M);
      int k0 = kp * 2, k1 = kp * 2 + 1;
      accv = __builtin_amdgcn_mfma_f32_16x16x16f16(av[k0], blo, accv, 0, 0, 0);
      accm = __builtin_amdgcn_mfma_f32_16x16x16f16(am[k0], blo, accm, 0, 0, 0);
      accr = __builtin_amdgcn_mfma_f32_16x16x16f16(ar[k0], alo, accr, 0, 0, 0);
      accv = __builtin_amdgcn_mfma_f32_16x16x16f16(av[k1], bhi, accv, 0, 0, 0);
      accm = __builtin_amdgcn_mfma_f32_16x16x16f16(am[k1], bhi, accm, 0, 0, 0);
      accr = __builtin_amdgcn_mfma_f32_16x16x16f16(ar[k1], ahi, accr, 0, 0, 0);
    }
    const int j = nt * 16 + li;
    const float bb = bias[j];
#pragma unroll
    for (int e = 0; e < 4; ++e) {
      size_t rr = (size_t)(rt + g * 4 + e);
      float v = accv[e] + bb;
      float m = accm[e] + bb;
      float d = accr[e];
      pxV[rr * G4 + j] = __float2half(v);
      pxI[rr * G4 + j] = __floats2half2_rn(m - d, m + d);
    }
  }
}

// Recurrence (R9 = best verified configuration, 1920-1932 µs — UNCHANGED):
// 128 blocks: blockIdx<64 -> val LSTM for batch row b; >=64 -> interval LSTM.
// 1024 threads: q=t&3 K-quarter, 4 rows/thread (j = (t>>2)*4+r); after quad
// reduce+sel4 thread t owns gate row t exactly.
// W tiers: r=0,1,2 VGPR-pinned (96 regs, asm), r=3 in LDS (128 KiB, loaded
// once). ZERO per-step global weight traffic (R10: streaming regresses).
// px prefetched one step ahead (bias pre-folded; intv = one half2(lb,ub)
// load); out stores deferred one step. sG intv = float2(gl,gu).
// Two-barrier skeleton is the verified optimum: R5/R7/R11 one-barrier
// variants regressed (lockstep serial tail); R8 LDS-only barriers neutral;
// R12 chain-shortened reduce regressed (DPP chain depth).
__global__ __launch_bounds__(1024, 4)
void lstm_kernel(const uint4* __restrict__ P4, const __half* __restrict__ px,
                 float* __restrict__ out) {
  __shared__ uint4 sLW[8192];                     // 128 KiB: W row-index r=3
  __shared__ __align__(16) __half sH[2][4][72];   // [slot][q][64+8 pad]; val: slot0=hv; intv: 0=hm,1=hr
  __shared__ __align__(16) float sG[2][G4];       // val: sG[0][row]; intv: aliased as float2[row]=(gl,gu)
  float2* sGp = (float2*)sG;
  const int t = threadIdx.x;
  const bool intv = blockIdx.x >= NB;
  const int b = intv ? blockIdx.x - NB : blockIdx.x;
  const int q = t & 3;
  // pinned W rows r=0,1,2 (96 VGPRs)
  uint4 Wp[3][8];
#pragma unroll
  for (int r = 0; r < 3; ++r)
#pragma unroll
    for (int c8 = 0; c8 < 8; ++c8)
      Wp[r][c8] = P4[((r * 8 + c8) << 10) + t];
#pragma unroll
  for (int r = 0; r < 3; ++r)
#pragma unroll
    for (int c8 = 0; c8 < 8; ++c8)
      asm volatile("" : "+v"(Wp[r][c8].x), "+v"(Wp[r][c8].y),
                        "+v"(Wp[r][c8].z), "+v"(Wp[r][c8].w));
  // stage r=3 into LDS (once; weights are step-invariant)
#pragma unroll
  for (int c8 = 0; c8 < 8; ++c8)
    sLW[(c8 << 10) + t] = P4[((24 + c8) << 10) + t];
  const bool is_tanh = ((t >> 8) == 2);           // rows 512..767 = gate g
  if (t < 288) ((unsigned*)sH)[t] = 0u;           // zero h (1152 B)
  __syncthreads();
  float* outb = out + (size_t)b * NT * NH;

  if (!intv) {
    // ---------------- point-value LSTM ----------------
    const __half* pxb = px + (size_t)b * NT * G4;
    float cv = 0.f, hv_p = 0.f;
    float pv = __half2float(pxb[t]);
    for (int ts = 0; ts < NT; ++ts) {
      if (ts > 0 && t < NH) outb[(size_t)(ts - 1) * NH + t] = hv_p;
      const int tsn = (ts + 1 < NT) ? ts + 1 : ts;
      float nv = __half2float(pxb[(size_t)tsn * G4 + t]);
      float A0 = 0.f, A1 = 0.f, A2 = 0.f, A3 = 0.f;
#pragma unroll
      for (int c8 = 0; c8 < 8; ++c8) {
        uint4 wl3 = sLW[(c8 << 10) + t];                // LDS r=3
        uint4 hv = *(const uint4*)(&sH[0][q][c8 * 8]);  // quad-distinct broadcast
        accV(Wp[0][c8], hv, A0);
        accV(Wp[1][c8], hv, A1);
        accV(Wp[2][c8], hv, A2);
        accV(wl3, hv, A3);
      }
      A0 = qsum4(A0); A1 = qsum4(A1); A2 = qsum4(A2); A3 = qsum4(A3);
      float av = sel4(A0, A1, A2, A3, q);               // row t
      float gt = gact(pv + av, is_tanh);                // bias pre-folded in px
      sG[0][t] = gt;
      __syncthreads();
      if (t < NH) {
        float iv = sG[0][t], fv = sG[0][NH + t], gv = sG[0][2 * NH + t], ov = sG[0][3 * NH + t];
        cv = fmaf(fv, cv, iv * gv);
        float hvn = ov * tanh_f(cv);
        hv_p = hvn;
        sH[0][t >> 6][t & 63] = __float2half(hvn);
      }
      __syncthreads();
      pv = nv;
    }
    if (t < NH) outb[(size_t)(NT - 1) * NH + t] = hv_p;
  } else {
    // ---------------- interval (lb/ub) LSTM ----------------
    const __half2* pI = (const __half2*)(px + CSTRIDE) + (size_t)b * NT * G4;
    float cl = 0.f, cu = 0.f, hl_p = 0.f, hu_p = 0.f;
    __half2 plu = pI[t];
    for (int ts = 0; ts < NT; ++ts) {
      if (ts > 0 && t < NH) {
        size_t o = (size_t)(ts - 1) * NH + t;
        outb[OSTRIDE + o] = hl_p; outb[2 * OSTRIDE + o] = hu_p;
      }
      const int tsn = (ts + 1 < NT) ? ts + 1 : ts;
      __half2 nlu = pI[(size_t)tsn * G4 + t];
      float M0 = 0.f, M1 = 0.f, M2 = 0.f, M3 = 0.f;
      float R0 = 0.f, R1 = 0.f, R2 = 0.f, R3 = 0.f;
#pragma unroll
      for (int c8 = 0; c8 < 8; ++c8) {
        uint4 wl3 = sLW[(c8 << 10) + t];                // LDS r=3
        uint4 hm = *(const uint4*)(&sH[0][q][c8 * 8]);
        uint4 hr = *(const uint4*)(&sH[1][q][c8 * 8]);
        accMR(Wp[0][c8], hm, hr, M0, R0);
        accMR(Wp[1][c8], hm, hr, M1, R1);
        accMR(Wp[2][c8], hm, hr, M2, R2);
        accMR(wl3, hm, hr, M3, R3);
      }
      M0 = qsum4(M0); M1 = qsum4(M1); M2 = qsum4(M2); M3 = qsum4(M3);
      R0 = qsum4(R0); R1 = qsum4(R1); R2 = qsum4(R2); R3 = qsum4(R3);
      float m = sel4(M0, M1, M2, M3, q);                // row t
      float d = sel4(R0, R1, R2, R3, q);
      float pl = __low2float(plu), pu = __high2float(plu);  // bias pre-folded
      float gl = gact(pl + (m - d), is_tanh);
      float gu = gact(pu + (m + d), is_tanh);
      sGp[t] = make_float2(gl, gu);                     // one b64 write
      __syncthreads();
      if (t < NH) {
        float2 gi = sGp[t], gf = sGp[NH + t], gg = sGp[2 * NH + t], go = sGp[3 * NH + t];
        float il = gi.x, iu = gi.y, fl = gf.x, fu = gf.y;
        float gl_ = gg.x, gu_ = gg.y, ol = go.x, ou = go.y;
        float p0 = fl*cl, p1 = fl*cu, p2 = fu*cl, p3 = fu*cu;
        float fcl = min4c(p0, p1, p2, p3);
        float fcu = max4c(p0, p1, p2, p3);
        p0 = il*gl_; p1 = il*gu_; p2 = iu*gl_; p3 = iu*gu_;
        float igl = min4c(p0, p1, p2, p3);
        float igu = max4c(p0, p1, p2, p3);
        cl = fcl + igl; cu = fcu + igu;
        float tl = tanh_f(cl), tu = tanh_f(cu);
        p0 = ol*tl; p1 = ol*tu; p2 = ou*tl; p3 = ou*tu;
        float hl = min4c(p0, p1, p2, p3);
        float hu = max4c(p0, p1, p2, p3);
        hl_p = hl; hu_p = hu;
        sH[0][t >> 6][t & 63] = __float2half(0.5f * (hl + hu));
        sH[1][t >> 6][t & 63] = __float2half(0.5f * (hu - hl));
      }
      __syncthreads();
      plu = nlu;
    }
    if (t < NH) {
      size_t o = (size_t)(NT - 1) * NH + t;
      outb[OSTRIDE + o] = hl_p; outb[2 * OSTRIDE + o] = hu_p;
    }
  }
}

extern "C" void kernel_launch(void* const* d_in, const int* in_sizes, int n_in,
                              void* d_out, int out_size, void* d_ws, size_t ws_size,
                              hipStream_t stream) {
  const float* xv   = (const float*)d_in[0];
  const float* xl   = (const float*)d_in[1];
  const float* xu   = (const float*)d_in[2];
  const float* Wih  = (const float*)d_in[3];
  const float* Whh  = (const float*)d_in[4];
  const float* bias = (const float*)d_in[5];
  float* out = (float*)d_out;
  char* ws = (char*)d_ws;
  uint4*  P4 = (uint4*)ws;                     // 512 KiB (recurrent W, 4-row layout)
  uint4*  PB = (uint4*)(ws + 512 * 1024);      // 256 KiB (px MFMA B-fragments)
  __half* px = (__half*)(ws + 768 * 1024);     // 192 MiB (val G4 + intv 2*G4 interleaved)

  conv_w_kernel<<<192, 256, 0, stream>>>(Whh, Wih, P4, PB);
  px_mfma<<<NBT / 64, 256, 0, stream>>>(xv, xl, xu, PB, bias, px);
  lstm_kernel<<<2 * NB, 1024, 0, stream>>>(P4, px, out);
}